// Round 17
// baseline (194.212 us; speedup 1.0000x reference)
//
#include <hip/hip_runtime.h>
#include <hip/hip_bf16.h>

#define D 128
#define EDGE_DIM 6
#define LN_EPS 1e-5f
#define HIST_BLOCKS 2048
#define BINE 1024     // edges per binning block
#define BNODE 64      // nodes per bucket
#define RCAP 2048     // LDS record capacity per bucket (mean 1024, sd 32)

typedef __attribute__((ext_vector_type(8))) short short8;
typedef __attribute__((ext_vector_type(4))) float f32x4;
typedef __attribute__((ext_vector_type(2))) float f32x2;

static __device__ __forceinline__ float bf_lo(unsigned u) { return __uint_as_float(u << 16); }
static __device__ __forceinline__ float bf_hi(unsigned u) { return __uint_as_float(u & 0xffff0000u); }
static __device__ __forceinline__ unsigned short f2bf(float f) {
    __hip_bfloat16 h = __float2bfloat16(f);
    return *reinterpret_cast<unsigned short*>(&h);
}
static __device__ __forceinline__ unsigned f2fp8(float f) {
    unsigned u;
    asm("v_cvt_pk_fp8_f32 %0, %1, %2" : "=v"(u) : "v"(f), "v"(0.0f));
    return u & 0xffu;
}
static __device__ __forceinline__ f32x2 cvt2_fp8v(unsigned w) {
    f32x2 r;
    asm("v_cvt_pk_f32_fp8 %0, %1" : "=v"(r) : "v"(w));
    return r;
}

// ---------- kernel 1: fused setup (unchanged) ----------
__global__ __launch_bounds__(128)
void setup_all(const float* __restrict__ Wn, const float* __restrict__ bn,
               const float* __restrict__ We, const float* __restrict__ be,
               const float* __restrict__ Wm, const float* __restrict__ bm,
               const int* __restrict__ ei, int E,
               float* __restrict__ Wnm, float* __restrict__ bnm,
               float* __restrict__ Wc, float* __restrict__ bc,
               int* __restrict__ cnt) {
    const int b = blockIdx.x;
    const int d = threadIdx.x;
    if (b < 128) {
        float acc = 0.f;
#pragma unroll 8
        for (int j = 0; j < D; ++j)
            acc = fmaf(Wn[b * D + j], Wm[j * D + d], acc);
        Wnm[b * D + d] = acc;
    } else if (b == 128) {
        float acc = 0.f;
#pragma unroll 8
        for (int j = 0; j < D; ++j)
            acc = fmaf(bn[j], Wm[j * D + d], acc);
        bnm[d] = acc;
    } else if (b < 135) {
        const int k = b - 129;
        float acc = 0.f;
#pragma unroll 8
        for (int j = 0; j < D; ++j)
            acc = fmaf(We[k * D + j], Wm[(D + j) * D + d], acc);
        Wc[k * D + d] = acc;
    } else if (b == 135) {
        float acc = bm[d];
#pragma unroll 8
        for (int j = 0; j < D; ++j)
            acc = fmaf(be[j], Wm[(D + j) * D + d], acc);
        bc[d] = acc;
    } else {
        for (int i = (b - 136) * 128 + d; i < E; i += HIST_BLOCKS * 128)
            atomicAdd(&cnt[ei[i]], 1);
    }
}

// ---------- kernel 2: block 0 = ordered bucket scan; blocks 1..4 = Wb pack ----------
__global__ __launch_bounds__(1024)
void bscan_pack(const int* __restrict__ cnt, int n, int nbuck,
                int* __restrict__ bstart, int* __restrict__ bcur,
                int* __restrict__ bcntb,
                const float* __restrict__ Wn, const float* __restrict__ Wnm,
                unsigned short* __restrict__ Wb) {
    const int tid = threadIdx.x;
    if (blockIdx.x > 0) {
        const int idx = ((int)blockIdx.x - 1) * 1024 + tid;  // 4096 fragments
        if (idx < 4096) {
            const int lane = idx & 63;
            const int s = (idx >> 6) & 3;
            const int ct = (idx >> 8) & 7;
            const int mat = idx >> 11;
            const float* W = mat ? Wnm : Wn;
            const int col = ct * 16 + (lane & 15);
            const int k0 = (lane >> 4) * 8 + 32 * s;
            short8 v;
#pragma unroll
            for (int j = 0; j < 8; ++j)
                v[j] = (short)f2bf(W[(size_t)(k0 + j) * D + col]);
            *reinterpret_cast<short8*>(Wb + (size_t)idx * 8) = v;
        }
        return;
    }
    __shared__ int wsum[16];
    const int lane = tid & 63, wid = tid >> 6;
    int v = 0;
    if (tid < nbuck) {
        const int base = tid * BNODE;
        const int lim = min(BNODE, n - base);
        for (int j = 0; j < lim; ++j) v += cnt[base + j];
    }
    int x = v;
#pragma unroll
    for (int off = 1; off < 64; off <<= 1) {
        int t = __shfl_up(x, off);
        if (lane >= off) x += t;
    }
    if (lane == 63) wsum[wid] = x;
    __syncthreads();
    if (wid == 0) {
        int w = (lane < 16) ? wsum[lane] : 0;
#pragma unroll
        for (int off = 1; off < 16; off <<= 1) {
            int t = __shfl_up(w, off);
            if (lane >= off) w += t;
        }
        if (lane < 16) wsum[lane] = w;
    }
    __syncthreads();
    const int woff = (wid > 0) ? wsum[wid - 1] : 0;
    if (tid < nbuck) {
        const int excl = woff + x - v;
        bstart[tid] = excl;
        bcur[tid] = excl;
        bcntb[tid] = v;
    }
}

// ---------- kernel 3: FUSED bucket-binning scatter + dual MFMA GEMM ----------
// Record (16B): w0 = col | rowLocal<<16 ; w1..w3 = ea as 3x(2xbf16).
// Bucket-grouped writes -> consecutive-position runs -> L2 merges lines.
__global__ __launch_bounds__(256)
void binscat_gemm(const int* __restrict__ ei, int E, const float* __restrict__ ea,
                  int* __restrict__ bcur, uint4* __restrict__ rec, int nbin, int nbuck,
                  const float* __restrict__ x, const unsigned short* __restrict__ Wb,
                  const float* __restrict__ bn, const float* __restrict__ bnm,
                  unsigned short* __restrict__ xtb, unsigned char* __restrict__ hb,
                  int nrows) {
    __shared__ unsigned sR[BINE * 3];   // 12 KB packed ea
    __shared__ int hist[800];
    __shared__ int cbase[800];
    const int tid = threadIdx.x;
    if ((int)blockIdx.x < nbin) {
        const int base = blockIdx.x * BINE;
        const int nrec = min(BINE, E - base);
        for (int b = tid; b < nbuck; b += 256) hist[b] = 0;
        const float2* ea2 = reinterpret_cast<const float2*>(ea);
        for (int i = tid; i < nrec * 3; i += 256) {
            float2 p = ea2[(size_t)base * 3 + i];
            sR[i] = (unsigned)f2bf(p.x) | ((unsigned)f2bf(p.y) << 16);
        }
        int rows[4], cols[4];
#pragma unroll
        for (int it = 0; it < 4; ++it) {
            const int e = base + it * 256 + tid;
            const bool val = e < E;
            rows[it] = val ? ei[e] : -1;
            cols[it] = val ? ei[E + e] : 0;
        }
        __syncthreads();
#pragma unroll
        for (int it = 0; it < 4; ++it)
            if (rows[it] >= 0) atomicAdd(&hist[rows[it] >> 6], 1);
        __syncthreads();
        for (int b = tid; b < nbuck; b += 256) {
            const int hv = hist[b];
            cbase[b] = hv ? atomicAdd(&bcur[b], hv) : 0;
            hist[b] = 0;
        }
        __syncthreads();
#pragma unroll
        for (int it = 0; it < 4; ++it)
            if (rows[it] >= 0) {
                const int bkt = rows[it] >> 6;
                const int lp = atomicAdd(&hist[bkt], 1);
                const int pos = cbase[bkt] + lp;
                const int le = (it * 256 + tid) * 3;
                const unsigned w0 = (unsigned)cols[it] | ((unsigned)(rows[it] & 63) << 16);
                rec[pos] = make_uint4(w0, sR[le], sR[le + 1], sR[le + 2]);
            }
        return;
    }
    // ----- dual MFMA GEMM: 4 waves/block, one 16-row tile per wave -----
    const int ntile = (nrows + 15) / 16;
    const int lane = tid & 63;
    const int wid = tid >> 6;
    const int t = ((int)blockIdx.x - nbin) * 4 + wid;
    if (t >= ntile) return;
    const int row16 = lane & 15;
    const int kgrp = lane >> 4;

    float biasA[8], biasB[8];
#pragma unroll
    for (int ct = 0; ct < 8; ++ct) {
        biasA[ct] = bn[ct * 16 + row16];
        biasB[ct] = bnm[ct * 16 + row16];
    }
    const int ra = t * 16 + row16;
    const bool rv = ra < nrows;
    short8 a[4];
#pragma unroll
    for (int s = 0; s < 4; ++s) {
        const float* xp = x + (size_t)ra * D + kgrp * 8 + 32 * s;
        float4 u0 = rv ? *reinterpret_cast<const float4*>(xp)
                       : make_float4(0.f, 0.f, 0.f, 0.f);
        float4 u1 = rv ? *reinterpret_cast<const float4*>(xp + 4)
                       : make_float4(0.f, 0.f, 0.f, 0.f);
        a[s][0] = (short)f2bf(u0.x); a[s][1] = (short)f2bf(u0.y);
        a[s][2] = (short)f2bf(u0.z); a[s][3] = (short)f2bf(u0.w);
        a[s][4] = (short)f2bf(u1.x); a[s][5] = (short)f2bf(u1.y);
        a[s][6] = (short)f2bf(u1.z); a[s][7] = (short)f2bf(u1.w);
    }
    const int rw0 = t * 16 + kgrp * 4;
#pragma unroll
    for (int mat = 0; mat < 2; ++mat) {
#pragma unroll
        for (int ct = 0; ct < 8; ++ct) {
            f32x4 acc = {0.f, 0.f, 0.f, 0.f};
#pragma unroll
            for (int s = 0; s < 4; ++s) {
                short8 bfr = *reinterpret_cast<const short8*>(
                    Wb + (size_t)((((mat * 8 + ct) * 4 + s) * 64 + lane)) * 8);
                acc = __builtin_amdgcn_mfma_f32_16x16x32_bf16(a[s], bfr, acc, 0, 0, 0);
            }
            const float bsc = mat ? biasB[ct] : biasA[ct];
            const int dcol = ct * 16 + row16;
#pragma unroll
            for (int j = 0; j < 4; ++j) {
                const int r = rw0 + j;
                if (r < nrows) {
                    if (mat == 0)
                        xtb[(size_t)r * D + dcol] = f2bf(acc[j] + bsc);
                    else
                        hb[(size_t)r * D + dcol] = (unsigned char)f2fp8(acc[j] + bsc);
                }
            }
        }
    }
}

// ---------- kernel 4: per-bucket aggregate: LDS sort-by-node, then R12 loop ----------
// 8 waves/block; records loaded coalesced then LDS-sorted (1 atomic + 1 write per
// edge); per-node loop reads records from LDS; h gathered fp8 (2 lines/edge).
__global__ __launch_bounds__(512)
void aggregate_ln(const unsigned char* __restrict__ h8,
                  const int* __restrict__ cnt,
                  const int* __restrict__ bstart, const int* __restrict__ bcntb,
                  const uint4* __restrict__ rec,
                  const float* __restrict__ Wc, const float* __restrict__ bc,
                  const unsigned* __restrict__ xtb,
                  const float* __restrict__ gamma, const float* __restrict__ beta,
                  float* __restrict__ out, int nnode) {
    __shared__ uint4 sRec[RCAP];        // 32 KB
    __shared__ int nstart[BNODE + 1];
    __shared__ int ncur[BNODE];
    const int tid = threadIdx.x;
    const int lane = tid & 63;
    const int wid = tid >> 6;  // 0..7

    const int b = blockIdx.x;
    const int nodes0 = b * BNODE;
    const int nn = min(BNODE, nnode - nodes0);

    if (wid == 0) {
        int v = (lane < nn) ? cnt[nodes0 + lane] : 0;
        int x = v;
#pragma unroll
        for (int off = 1; off < 64; off <<= 1) {
            int t = __shfl_up(x, off);
            if (lane >= off) x += t;
        }
        nstart[lane + 1] = x;
        if (lane == 0) nstart[0] = 0;
        ncur[lane] = x - v;  // exclusive
    }

    f32x2 wc[EDGE_DIM];
#pragma unroll
    for (int k = 0; k < EDGE_DIM; ++k)
        wc[k] = reinterpret_cast<const f32x2*>(Wc)[k * 64 + lane];
    const f32x2 bc2 = reinterpret_cast<const f32x2*>(bc)[lane];
    const f32x2 g = reinterpret_cast<const f32x2*>(gamma)[lane];
    const f32x2 bb = reinterpret_cast<const f32x2*>(beta)[lane];
    __syncthreads();

    const int s = bstart[b];
    const int nrec = min(bcntb[b], RCAP);
    for (int i = tid; i < nrec; i += 512) {
        uint4 rd = rec[(size_t)s + i];
        const int rl = (rd.x >> 16) & 63;
        const int pos = atomicAdd(&ncur[rl], 1);
        sRec[pos] = rd;
    }
    __syncthreads();

    for (int k = wid; k < nn; k += 8) {
        const int gnode = nodes0 + k;
        const int ls = nstart[k];
        const int c = nstart[k + 1] - ls;
        const unsigned xu = xtb[(unsigned)(gnode * 64 + lane)];
        f32x2 axy = {0.f, 0.f};
        for (int ibase = 0; ibase < c; ibase += 64) {
            const int m = min(64, c - ibase);
            uint4 rc = make_uint4(0, 0, 0, 0);
            if (lane < m) rc = sRec[ls + ibase + lane];
            auto LDH = [&](int j) -> unsigned {
                const int jc = min(j, m - 1);
                const unsigned colj =
                    (unsigned)__builtin_amdgcn_readlane((int)rc.x, jc) & 0xffffu;
                const unsigned short* hrow =
                    reinterpret_cast<const unsigned short*>(h8 + ((size_t)colj << 7));
                return hrow[lane];  // 2 fp8 = dims (2l, 2l+1)
            };
            auto COMP = [&](int j, unsigned hv) {
                const unsigned b01 = (unsigned)__builtin_amdgcn_readlane((int)rc.y, j);
                const unsigned b23 = (unsigned)__builtin_amdgcn_readlane((int)rc.z, j);
                const unsigned b45 = (unsigned)__builtin_amdgcn_readlane((int)rc.w, j);
                f32x2 e01, e23, e45, mA, mB;
                e01[0] = bf_lo(b01); e01[1] = bf_hi(b01);
                e23[0] = bf_lo(b23); e23[1] = bf_hi(b23);
                e45[0] = bf_lo(b45); e45[1] = bf_hi(b45);
                const f32x2 hx = cvt2_fp8v(hv);
                asm("v_pk_add_f32 %0, %1, %2" : "=v"(mA) : "v"(bc2), "v"(hx));
                asm("v_pk_mul_f32 %0, %1, %2 op_sel:[1,0] op_sel_hi:[1,1]"
                    : "=v"(mB) : "s"(e01), "v"(wc[1]));
                asm("v_pk_fma_f32 %0, %1, %2, %0 op_sel:[0,0,0] op_sel_hi:[0,1,1]"
                    : "+v"(mA) : "s"(e01), "v"(wc[0]));
                asm("v_pk_fma_f32 %0, %1, %2, %0 op_sel:[1,0,0] op_sel_hi:[1,1,1]"
                    : "+v"(mB) : "s"(e23), "v"(wc[3]));
                asm("v_pk_fma_f32 %0, %1, %2, %0 op_sel:[0,0,0] op_sel_hi:[0,1,1]"
                    : "+v"(mA) : "s"(e23), "v"(wc[2]));
                asm("v_pk_fma_f32 %0, %1, %2, %0 op_sel:[1,0,0] op_sel_hi:[1,1,1]"
                    : "+v"(mB) : "s"(e45), "v"(wc[5]));
                asm("v_pk_fma_f32 %0, %1, %2, %0 op_sel:[0,0,0] op_sel_hi:[0,1,1]"
                    : "+v"(mA) : "s"(e45), "v"(wc[4]));
                asm("v_pk_add_f32 %0, %0, %1" : "+v"(mA) : "v"(mB));
                axy[0] += fmaxf(mA[0], 0.f);
                axy[1] += fmaxf(mA[1], 0.f);
            };
            unsigned h0 = LDH(0), h1 = LDH(1), h2 = LDH(2), h3 = LDH(3),
                     h4 = LDH(4), h5 = LDH(5), h6 = LDH(6), h7 = LDH(7);
            int i = 0;
            for (; i + 8 <= m; i += 8) {
                COMP(i + 0, h0); h0 = LDH(i + 8);
                COMP(i + 1, h1); h1 = LDH(i + 9);
                COMP(i + 2, h2); h2 = LDH(i + 10);
                COMP(i + 3, h3); h3 = LDH(i + 11);
                COMP(i + 4, h4); h4 = LDH(i + 12);
                COMP(i + 5, h5); h5 = LDH(i + 13);
                COMP(i + 6, h6); h6 = LDH(i + 14);
                COMP(i + 7, h7); h7 = LDH(i + 15);
            }
            if (i + 0 < m) COMP(i + 0, h0);
            if (i + 1 < m) COMP(i + 1, h1);
            if (i + 2 < m) COMP(i + 2, h2);
            if (i + 3 < m) COMP(i + 3, h3);
            if (i + 4 < m) COMP(i + 4, h4);
            if (i + 5 < m) COMP(i + 5, h5);
            if (i + 6 < m) COMP(i + 6, h6);
        }
        const float inv = 1.0f / fmaxf((float)c, 1.0f);
        float o0 = fmaf(axy[0], inv, bf_lo(xu));
        float o1 = fmaf(axy[1], inv, bf_hi(xu));
        float s1 = o0 + o1, s2 = o0 * o0 + o1 * o1;
#pragma unroll
        for (int off = 32; off; off >>= 1) {
            s1 += __shfl_xor(s1, off);
            s2 += __shfl_xor(s2, off);
        }
        const float mean = s1 * (1.0f / D);
        const float var = s2 * (1.0f / D) - mean * mean;
        const float rstd = rsqrtf(var + LN_EPS);
        float2 r;
        r.x = (o0 - mean) * rstd * g[0] + bb[0];
        r.y = (o1 - mean) * rstd * g[1] + bb[1];
        reinterpret_cast<float2*>(out)[(size_t)gnode * 64 + lane] = r;
    }
}

extern "C" void kernel_launch(void* const* d_in, const int* in_sizes, int n_in,
                              void* d_out, int out_size, void* d_ws, size_t ws_size,
                              hipStream_t stream) {
    const float* x     = (const float*)d_in[0];
    const float* eattr = (const float*)d_in[1];
    const float* Wn    = (const float*)d_in[2];
    const float* bn    = (const float*)d_in[3];
    const float* We    = (const float*)d_in[4];
    const float* be    = (const float*)d_in[5];
    const float* Wm    = (const float*)d_in[6];
    const float* bm    = (const float*)d_in[7];
    const float* gamma = (const float*)d_in[8];
    const float* beta  = (const float*)d_in[9];
    const int*   ei    = (const int*)d_in[10];

    const int N = in_sizes[0] / D;
    const int E = in_sizes[10] / 2;
    const int nbuck = (N + BNODE - 1) / BNODE;  // 782 (must be <= 800)

    char* ws = (char*)d_ws;
    unsigned short* xtb = (unsigned short*)ws; ws += (size_t)N * D * 2;
    unsigned char*  hb  = (unsigned char*)ws;  ws += (size_t)N * D;
    int* cnt    = (int*)ws;                    ws += (size_t)N * 4;
    int* bstart = (int*)ws;                    ws += (size_t)(nbuck + 1) * 4;
    int* bcur   = (int*)ws;                    ws += (size_t)(nbuck + 1) * 4;
    int* bcntb  = (int*)ws;                    ws += (size_t)(nbuck + 1) * 4;
    uint4* rec  = (uint4*)ws;                  ws += (size_t)E * 16;
    float* Wnm  = (float*)ws;                  ws += (size_t)D * D * 4;
    float* bnm  = (float*)ws;                  ws += (size_t)D * 4;
    float* Wc   = (float*)ws;                  ws += (size_t)EDGE_DIM * D * 4;
    float* bcv  = (float*)ws;                  ws += (size_t)D * 4;
    unsigned short* Wb = (unsigned short*)ws;  ws += (size_t)4096 * 8 * 2;

    const int nbin = (E + BINE - 1) / BINE;
    const int ntile = (N + 15) / 16;

    hipMemsetAsync(cnt, 0, (size_t)N * 4, stream);

    setup_all<<<136 + HIST_BLOCKS, 128, 0, stream>>>(Wn, bn, We, be, Wm, bm, ei, E,
                                                     Wnm, bnm, Wc, bcv, cnt);
    bscan_pack<<<5, 1024, 0, stream>>>(cnt, N, nbuck, bstart, bcur, bcntb, Wn, Wnm, Wb);
    binscat_gemm<<<nbin + (ntile + 3) / 4, 256, 0, stream>>>(
        ei, E, eattr, bcur, rec, nbin, nbuck, x, Wb, bn, bnm, xtb, hb, N);
    aggregate_ln<<<nbuck, 512, 0, stream>>>(hb, cnt, bstart, bcntb, rec,
                                            Wc, bcv, (const unsigned*)xtb,
                                            gamma, beta, (float*)d_out, N);
}

// Round 18
// 152.391 us; speedup vs baseline: 1.2744x; 1.2744x over previous
//
#include <hip/hip_runtime.h>
#include <hip/hip_bf16.h>

#define D 128
#define EDGE_DIM 6
#define LN_EPS 1e-5f
#define HIST_BLOCKS 2048
#define BINE 2048     // edges per binning tile
#define CB 512        // nodes per coarse bucket
#define NB2 98        // ceil(50000/512)

typedef __attribute__((ext_vector_type(8))) short short8;
typedef __attribute__((ext_vector_type(4))) float f32x4;
typedef __attribute__((ext_vector_type(2))) float f32x2;

static __device__ __forceinline__ float bf_lo(unsigned u) { return __uint_as_float(u << 16); }
static __device__ __forceinline__ float bf_hi(unsigned u) { return __uint_as_float(u & 0xffff0000u); }
static __device__ __forceinline__ unsigned short f2bf(float f) {
    __hip_bfloat16 h = __float2bfloat16(f);
    return *reinterpret_cast<unsigned short*>(&h);
}
static __device__ __forceinline__ unsigned f2fp8(float f) {
    unsigned u;
    asm("v_cvt_pk_fp8_f32 %0, %1, %2" : "=v"(u) : "v"(f), "v"(0.0f));
    return u & 0xffu;
}
static __device__ __forceinline__ f32x2 cvt2_fp8v(unsigned w) {
    f32x2 r;
    asm("v_cvt_pk_f32_fp8 %0, %1" : "=v"(r) : "v"(w));
    return r;
}

// ---------- kernel 1: fused setup (unchanged) ----------
__global__ __launch_bounds__(128)
void setup_all(const float* __restrict__ Wn, const float* __restrict__ bn,
               const float* __restrict__ We, const float* __restrict__ be,
               const float* __restrict__ Wm, const float* __restrict__ bm,
               const int* __restrict__ ei, int E,
               float* __restrict__ Wnm, float* __restrict__ bnm,
               float* __restrict__ Wc, float* __restrict__ bc,
               int* __restrict__ cnt) {
    const int b = blockIdx.x;
    const int d = threadIdx.x;
    if (b < 128) {
        float acc = 0.f;
#pragma unroll 8
        for (int j = 0; j < D; ++j)
            acc = fmaf(Wn[b * D + j], Wm[j * D + d], acc);
        Wnm[b * D + d] = acc;
    } else if (b == 128) {
        float acc = 0.f;
#pragma unroll 8
        for (int j = 0; j < D; ++j)
            acc = fmaf(bn[j], Wm[j * D + d], acc);
        bnm[d] = acc;
    } else if (b < 135) {
        const int k = b - 129;
        float acc = 0.f;
#pragma unroll 8
        for (int j = 0; j < D; ++j)
            acc = fmaf(We[k * D + j], Wm[(D + j) * D + d], acc);
        Wc[k * D + d] = acc;
    } else if (b == 135) {
        float acc = bm[d];
#pragma unroll 8
        for (int j = 0; j < D; ++j)
            acc = fmaf(be[j], Wm[(D + j) * D + d], acc);
        bc[d] = acc;
    } else {
        for (int i = (b - 136) * 128 + d; i < E; i += HIST_BLOCKS * 128)
            atomicAdd(&cnt[ei[i]], 1);
    }
}

// ---------- kernel 2: scan (+ coarse cursors) / Wb pack ----------
// Node-level exclusive scan (atomic block base: segments disjoint, node-order
// contiguous WITHIN each 1024-node scan block; CB=512 divides 1024 so every
// coarse bucket is contiguous). Emits cur2[b]=start[b*512].
__global__ __launch_bounds__(1024)
void scan_pack(const int* __restrict__ cnt, int* __restrict__ start,
               int* __restrict__ cur2, int* __restrict__ cursor, int n, int nscan,
               const float* __restrict__ Wn, const float* __restrict__ Wnm,
               unsigned short* __restrict__ Wb) {
    const int tid = threadIdx.x;
    if ((int)blockIdx.x >= nscan) {
        const int idx = ((int)blockIdx.x - nscan) * 1024 + tid;  // 4096 fragments
        if (idx < 4096) {
            const int lane = idx & 63;
            const int s = (idx >> 6) & 3;
            const int ct = (idx >> 8) & 7;
            const int mat = idx >> 11;
            const float* W = mat ? Wnm : Wn;
            const int col = ct * 16 + (lane & 15);
            const int k0 = (lane >> 4) * 8 + 32 * s;
            short8 v;
#pragma unroll
            for (int j = 0; j < 8; ++j)
                v[j] = (short)f2bf(W[(size_t)(k0 + j) * D + col]);
            *reinterpret_cast<short8*>(Wb + (size_t)idx * 8) = v;
        }
        return;
    }
    __shared__ int wsum[16];
    __shared__ int sbase;
    const int lane = tid & 63, wid = tid >> 6;
    const int i = blockIdx.x * 1024 + tid;
    const int v = (i < n) ? cnt[i] : 0;
    int x = v;
#pragma unroll
    for (int off = 1; off < 64; off <<= 1) {
        int t = __shfl_up(x, off);
        if (lane >= off) x += t;
    }
    if (lane == 63) wsum[wid] = x;
    __syncthreads();
    if (wid == 0) {
        int w = (lane < 16) ? wsum[lane] : 0;
#pragma unroll
        for (int off = 1; off < 16; off <<= 1) {
            int t = __shfl_up(w, off);
            if (lane >= off) w += t;
        }
        if (lane < 16) wsum[lane] = w;
    }
    __syncthreads();
    const int total = wsum[15];
    if (tid == 0) sbase = atomicAdd(cursor, total);
    __syncthreads();
    const int woff = (wid > 0) ? wsum[wid - 1] : 0;
    if (i < n) {
        const int sv = sbase + woff + x - v;
        start[i] = sv;
        if ((i & (CB - 1)) == 0) cur2[i >> 9] = sv;  // coarse bucket cursor
    }
}

// ---------- kernel 3: FUSED coarse-binning scatter + dual MFMA GEMM ----------
// tmp record (16B): w0 = col(16b) | rowLocal(9b)<<16 ; w1..w3 = ea 3x(2xbf16).
// 98 coarse buckets -> runs of ~21 records -> L2 merges write lines.
__global__ __launch_bounds__(256)
void scat_gemm(const int* __restrict__ ei, int E, const float* __restrict__ ea,
               int* __restrict__ cur2, uint4* __restrict__ tmp, int nbin,
               const float* __restrict__ x, const unsigned short* __restrict__ Wb,
               const float* __restrict__ bn, const float* __restrict__ bnm,
               unsigned short* __restrict__ xtb, unsigned char* __restrict__ hb,
               int nrows) {
    __shared__ unsigned sR[BINE * 3];  // 24 KB packed ea
    __shared__ int hist[NB2];
    __shared__ int cbase[NB2];
    const int tid = threadIdx.x;
    if ((int)blockIdx.x < nbin) {
        const int base = blockIdx.x * BINE;
        const int nrec = min(BINE, E - base);
        if (tid < NB2) hist[tid] = 0;
        const float2* ea2 = reinterpret_cast<const float2*>(ea);
        for (int i = tid; i < nrec * 3; i += 256) {
            float2 p = ea2[(size_t)base * 3 + i];
            sR[i] = (unsigned)f2bf(p.x) | ((unsigned)f2bf(p.y) << 16);
        }
        int rows[8], cols[8];
#pragma unroll
        for (int it = 0; it < 8; ++it) {
            const int e = base + it * 256 + tid;
            const bool val = e < E;
            rows[it] = val ? ei[e] : -1;
            cols[it] = val ? ei[E + e] : 0;
        }
        __syncthreads();
#pragma unroll
        for (int it = 0; it < 8; ++it)
            if (rows[it] >= 0) atomicAdd(&hist[rows[it] >> 9], 1);
        __syncthreads();
        if (tid < NB2) {
            const int hv = hist[tid];
            cbase[tid] = hv ? atomicAdd(&cur2[tid], hv) : 0;
            hist[tid] = 0;
        }
        __syncthreads();
#pragma unroll
        for (int it = 0; it < 8; ++it)
            if (rows[it] >= 0) {
                const int bkt = rows[it] >> 9;
                const int lp = atomicAdd(&hist[bkt], 1);
                const int pos = cbase[bkt] + lp;
                const int le = (it * 256 + tid) * 3;
                const unsigned w0 = (unsigned)cols[it] | ((unsigned)(rows[it] & (CB - 1)) << 16);
                tmp[pos] = make_uint4(w0, sR[le], sR[le + 1], sR[le + 2]);
            }
        return;
    }
    // ----- dual MFMA GEMM: 4 waves/block, one 16-row tile per wave -----
    const int ntile = (nrows + 15) / 16;
    const int lane = tid & 63;
    const int wid = tid >> 6;
    const int t = ((int)blockIdx.x - nbin) * 4 + wid;
    if (t >= ntile) return;
    const int row16 = lane & 15;
    const int kgrp = lane >> 4;

    float biasA[8], biasB[8];
#pragma unroll
    for (int ct = 0; ct < 8; ++ct) {
        biasA[ct] = bn[ct * 16 + row16];
        biasB[ct] = bnm[ct * 16 + row16];
    }
    const int ra = t * 16 + row16;
    const bool rv = ra < nrows;
    short8 a[4];
#pragma unroll
    for (int s = 0; s < 4; ++s) {
        const float* xp = x + (size_t)ra * D + kgrp * 8 + 32 * s;
        float4 u0 = rv ? *reinterpret_cast<const float4*>(xp)
                       : make_float4(0.f, 0.f, 0.f, 0.f);
        float4 u1 = rv ? *reinterpret_cast<const float4*>(xp + 4)
                       : make_float4(0.f, 0.f, 0.f, 0.f);
        a[s][0] = (short)f2bf(u0.x); a[s][1] = (short)f2bf(u0.y);
        a[s][2] = (short)f2bf(u0.z); a[s][3] = (short)f2bf(u0.w);
        a[s][4] = (short)f2bf(u1.x); a[s][5] = (short)f2bf(u1.y);
        a[s][6] = (short)f2bf(u1.z); a[s][7] = (short)f2bf(u1.w);
    }
    const int rw0 = t * 16 + kgrp * 4;
#pragma unroll
    for (int mat = 0; mat < 2; ++mat) {
#pragma unroll
        for (int ct = 0; ct < 8; ++ct) {
            f32x4 acc = {0.f, 0.f, 0.f, 0.f};
#pragma unroll
            for (int s = 0; s < 4; ++s) {
                short8 bfr = *reinterpret_cast<const short8*>(
                    Wb + (size_t)((((mat * 8 + ct) * 4 + s) * 64 + lane)) * 8);
                acc = __builtin_amdgcn_mfma_f32_16x16x32_bf16(a[s], bfr, acc, 0, 0, 0);
            }
            const float bsc = mat ? biasB[ct] : biasA[ct];
            const int dcol = ct * 16 + row16;
#pragma unroll
            for (int j = 0; j < 4; ++j) {
                const int r = rw0 + j;
                if (r < nrows) {
                    if (mat == 0)
                        xtb[(size_t)r * D + dcol] = f2bf(acc[j] + bsc);
                    else
                        hb[(size_t)r * D + dcol] = (unsigned char)f2fp8(acc[j] + bsc);
                }
            }
        }
    }
}

// ---------- kernel 4: resort — coarse records -> exact node-CSR order ----------
// One block per coarse bucket; LDS-staged chunks; positions from LDS ncur seeded
// by start[] (1 LDS atomic/edge). All writes land in the bucket's 128KB region
// from this single block -> single XCD L2 -> merged full-line evictions.
__global__ __launch_bounds__(512)
void resort(const uint4* __restrict__ tmp, const int* __restrict__ start,
            const int* __restrict__ cnt, uint4* __restrict__ rec, int nnode) {
    __shared__ uint4 sRec[2048];   // 32 KB
    __shared__ int ncur[CB];
    const int tid = threadIdx.x;
    const int b = blockIdx.x;
    const int nodes0 = b * CB;
    const int nn = min(CB, nnode - nodes0);
    if (tid < CB) ncur[tid] = (tid < nn) ? start[nodes0 + tid] : 0;
    __syncthreads();
    const int s0 = start[nodes0];
    const int lastn = nodes0 + nn - 1;
    const int count = start[lastn] + cnt[lastn] - s0;
    for (int base = 0; base < count; base += 2048) {
        const int m = min(2048, count - base);
        for (int i = tid; i < m; i += 512)
            sRec[i] = tmp[(size_t)(s0 + base) + i];
        __syncthreads();
        for (int i = tid; i < m; i += 512) {
            const uint4 rd = sRec[i];
            const int rl = (rd.x >> 16) & (CB - 1);
            const int pos = atomicAdd(&ncur[rl], 1);
            rec[pos] = make_uint4(rd.x & 0xffffu, rd.y, rd.z, rd.w);
        }
        __syncthreads();
    }
}

// ---------- kernel 5: per-node gather-aggregate + residual + LayerNorm ----------
// (R15 version verbatim: fp8 h, 2 lines/edge, pk-MLP.)
__global__ __launch_bounds__(256)
void aggregate_ln(const unsigned char* __restrict__ h8,
                  const int* __restrict__ start, const int* __restrict__ cnt,
                  const uint4* __restrict__ rec,
                  const float* __restrict__ Wc, const float* __restrict__ bc,
                  const unsigned* __restrict__ xtb,
                  const float* __restrict__ gamma, const float* __restrict__ beta,
                  float* __restrict__ out, int nnode) {
    const int lane = threadIdx.x & 63;
    const int wid = threadIdx.x >> 6;

    f32x2 wc[EDGE_DIM];
#pragma unroll
    for (int k = 0; k < EDGE_DIM; ++k)
        wc[k] = reinterpret_cast<const f32x2*>(Wc)[k * 64 + lane];
    const f32x2 bc2 = reinterpret_cast<const f32x2*>(bc)[lane];
    const f32x2 g = reinterpret_cast<const f32x2*>(gamma)[lane];
    const f32x2 bb = reinterpret_cast<const f32x2*>(beta)[lane];

    for (int n = blockIdx.x * 4 + wid; n < nnode; n += gridDim.x * 4) {
        const int s = start[n];
        const int c = cnt[n];
        const unsigned xu = xtb[(unsigned)(n * 64 + lane)];
        f32x2 axy = {0.f, 0.f};
        for (int ibase = 0; ibase < c; ibase += 64) {
            const int m = min(64, c - ibase);
            uint4 rc = make_uint4(0, 0, 0, 0);
            if (lane < m) rc = rec[(size_t)(s + ibase) + lane];
            auto LDH = [&](int j) -> unsigned {
                const int jc = min(j, m - 1);
                const unsigned colj = (unsigned)__builtin_amdgcn_readlane((int)rc.x, jc);
                const unsigned short* hrow =
                    reinterpret_cast<const unsigned short*>(h8 + ((size_t)colj << 7));
                return hrow[lane];  // 2 fp8 = dims (2l, 2l+1)
            };
            auto COMP = [&](int j, unsigned hv) {
                const unsigned b01 = (unsigned)__builtin_amdgcn_readlane((int)rc.y, j);
                const unsigned b23 = (unsigned)__builtin_amdgcn_readlane((int)rc.z, j);
                const unsigned b45 = (unsigned)__builtin_amdgcn_readlane((int)rc.w, j);
                f32x2 e01, e23, e45, mA, mB;
                e01[0] = bf_lo(b01); e01[1] = bf_hi(b01);
                e23[0] = bf_lo(b23); e23[1] = bf_hi(b23);
                e45[0] = bf_lo(b45); e45[1] = bf_hi(b45);
                const f32x2 hx = cvt2_fp8v(hv);
                asm("v_pk_add_f32 %0, %1, %2" : "=v"(mA) : "v"(bc2), "v"(hx));
                asm("v_pk_mul_f32 %0, %1, %2 op_sel:[1,0] op_sel_hi:[1,1]"
                    : "=v"(mB) : "s"(e01), "v"(wc[1]));
                asm("v_pk_fma_f32 %0, %1, %2, %0 op_sel:[0,0,0] op_sel_hi:[0,1,1]"
                    : "+v"(mA) : "s"(e01), "v"(wc[0]));
                asm("v_pk_fma_f32 %0, %1, %2, %0 op_sel:[1,0,0] op_sel_hi:[1,1,1]"
                    : "+v"(mB) : "s"(e23), "v"(wc[3]));
                asm("v_pk_fma_f32 %0, %1, %2, %0 op_sel:[0,0,0] op_sel_hi:[0,1,1]"
                    : "+v"(mA) : "s"(e23), "v"(wc[2]));
                asm("v_pk_fma_f32 %0, %1, %2, %0 op_sel:[1,0,0] op_sel_hi:[1,1,1]"
                    : "+v"(mB) : "s"(e45), "v"(wc[5]));
                asm("v_pk_fma_f32 %0, %1, %2, %0 op_sel:[0,0,0] op_sel_hi:[0,1,1]"
                    : "+v"(mA) : "s"(e45), "v"(wc[4]));
                asm("v_pk_add_f32 %0, %0, %1" : "+v"(mA) : "v"(mB));
                axy[0] += fmaxf(mA[0], 0.f);
                axy[1] += fmaxf(mA[1], 0.f);
            };
            unsigned h0 = LDH(0), h1 = LDH(1), h2 = LDH(2), h3 = LDH(3),
                     h4 = LDH(4), h5 = LDH(5), h6 = LDH(6), h7 = LDH(7);
            int i = 0;
            for (; i + 8 <= m; i += 8) {
                COMP(i + 0, h0); h0 = LDH(i + 8);
                COMP(i + 1, h1); h1 = LDH(i + 9);
                COMP(i + 2, h2); h2 = LDH(i + 10);
                COMP(i + 3, h3); h3 = LDH(i + 11);
                COMP(i + 4, h4); h4 = LDH(i + 12);
                COMP(i + 5, h5); h5 = LDH(i + 13);
                COMP(i + 6, h6); h6 = LDH(i + 14);
                COMP(i + 7, h7); h7 = LDH(i + 15);
            }
            if (i + 0 < m) COMP(i + 0, h0);
            if (i + 1 < m) COMP(i + 1, h1);
            if (i + 2 < m) COMP(i + 2, h2);
            if (i + 3 < m) COMP(i + 3, h3);
            if (i + 4 < m) COMP(i + 4, h4);
            if (i + 5 < m) COMP(i + 5, h5);
            if (i + 6 < m) COMP(i + 6, h6);
        }
        const float inv = 1.0f / fmaxf((float)c, 1.0f);
        float o0 = fmaf(axy[0], inv, bf_lo(xu));
        float o1 = fmaf(axy[1], inv, bf_hi(xu));
        float s1 = o0 + o1, s2 = o0 * o0 + o1 * o1;
#pragma unroll
        for (int off = 32; off; off >>= 1) {
            s1 += __shfl_xor(s1, off);
            s2 += __shfl_xor(s2, off);
        }
        const float mean = s1 * (1.0f / D);
        const float var = s2 * (1.0f / D) - mean * mean;
        const float rstd = rsqrtf(var + LN_EPS);
        float2 r;
        r.x = (o0 - mean) * rstd * g[0] + bb[0];
        r.y = (o1 - mean) * rstd * g[1] + bb[1];
        reinterpret_cast<float2*>(out)[(size_t)n * 64 + lane] = r;
    }
}

extern "C" void kernel_launch(void* const* d_in, const int* in_sizes, int n_in,
                              void* d_out, int out_size, void* d_ws, size_t ws_size,
                              hipStream_t stream) {
    const float* x     = (const float*)d_in[0];
    const float* eattr = (const float*)d_in[1];
    const float* Wn    = (const float*)d_in[2];
    const float* bn    = (const float*)d_in[3];
    const float* We    = (const float*)d_in[4];
    const float* be    = (const float*)d_in[5];
    const float* Wm    = (const float*)d_in[6];
    const float* bm    = (const float*)d_in[7];
    const float* gamma = (const float*)d_in[8];
    const float* beta  = (const float*)d_in[9];
    const int*   ei    = (const int*)d_in[10];

    const int N = in_sizes[0] / D;
    const int E = in_sizes[10] / 2;
    const int nbuck2 = (N + CB - 1) / CB;  // 98

    char* ws = (char*)d_ws;
    unsigned short* xtb = (unsigned short*)ws; ws += (size_t)N * D * 2;
    unsigned char*  hb  = (unsigned char*)ws;  ws += (size_t)N * D;
    int* ints = (int*)ws;                      ws += (size_t)(N + 4) * 4;  // cnt, cursor
    int* cnt = ints;
    int* cursor = ints + N;
    int* cur2   = (int*)ws;                    ws += (size_t)(nbuck2 + 1) * 4;
    int* startv = (int*)ws;                    ws += (size_t)N * 4;
    uint4* rec  = (uint4*)ws;                  ws += (size_t)E * 16;
    float* Wnm  = (float*)ws;                  ws += (size_t)D * D * 4;
    float* bnm  = (float*)ws;                  ws += (size_t)D * 4;
    float* Wc   = (float*)ws;                  ws += (size_t)EDGE_DIM * D * 4;
    float* bcv  = (float*)ws;                  ws += (size_t)D * 4;
    unsigned short* Wb = (unsigned short*)ws;  ws += (size_t)4096 * 8 * 2;

    uint4* tmp = (uint4*)d_out;  // 12.8MB scratch; aggregate overwrites d_out last

    const int nscan = (N + 1023) / 1024;
    const int nbin = (E + BINE - 1) / BINE;
    const int ntile = (N + 15) / 16;

    hipMemsetAsync(ints, 0, (size_t)(N + 4) * 4, stream);

    setup_all<<<136 + HIST_BLOCKS, 128, 0, stream>>>(Wn, bn, We, be, Wm, bm, ei, E,
                                                     Wnm, bnm, Wc, bcv, cnt);
    scan_pack<<<nscan + 4, 1024, 0, stream>>>(cnt, startv, cur2, cursor, N, nscan,
                                              Wn, Wnm, Wb);
    scat_gemm<<<nbin + (ntile + 3) / 4, 256, 0, stream>>>(ei, E, eattr, cur2, tmp, nbin,
                                                          x, Wb, bn, bnm, xtb, hb, N);
    resort<<<nbuck2, 512, 0, stream>>>(tmp, startv, cnt, rec, N);
    aggregate_ln<<<(N + 3) / 4, 256, 0, stream>>>(hb, startv, cnt, rec,
                                                  Wc, bcv, (const unsigned*)xtb,
                                                  gamma, beta, (float*)d_out, N);
}

// Round 19
// 149.764 us; speedup vs baseline: 1.2968x; 1.0175x over previous
//
#include <hip/hip_runtime.h>
#include <hip/hip_bf16.h>

#define D 128
#define EDGE_DIM 6
#define LN_EPS 1e-5f
#define HIST_BLOCKS 2048
#define BINE 2048     // edges per binning tile
#define CB 256        // nodes per coarse bucket
#define NB2 196       // ceil(50000/256)

typedef __attribute__((ext_vector_type(8))) short short8;
typedef __attribute__((ext_vector_type(4))) float f32x4;
typedef __attribute__((ext_vector_type(2))) float f32x2;

static __device__ __forceinline__ float bf_lo(unsigned u) { return __uint_as_float(u << 16); }
static __device__ __forceinline__ float bf_hi(unsigned u) { return __uint_as_float(u & 0xffff0000u); }
static __device__ __forceinline__ unsigned short f2bf(float f) {
    __hip_bfloat16 h = __float2bfloat16(f);
    return *reinterpret_cast<unsigned short*>(&h);
}
static __device__ __forceinline__ unsigned f2fp8(float f) {
    unsigned u;
    asm("v_cvt_pk_fp8_f32 %0, %1, %2" : "=v"(u) : "v"(f), "v"(0.0f));
    return u & 0xffu;
}
// pack 2 f32 -> 2 fp8 e4m3 (low 16 bits)
static __device__ __forceinline__ unsigned f2fp8pair(float a, float b) {
    unsigned u;
    asm("v_cvt_pk_fp8_f32 %0, %1, %2" : "=v"(u) : "v"(a), "v"(b));
    return u & 0xffffu;
}
// decode 2 fp8 (low 16b, SGPR-or-VGPR input via v; separate s variant below)
static __device__ __forceinline__ f32x2 cvt2_fp8v(unsigned w) {
    f32x2 r;
    asm("v_cvt_pk_f32_fp8 %0, %1" : "=v"(r) : "v"(w));
    return r;
}
static __device__ __forceinline__ f32x2 cvt2_fp8s(unsigned w) {
    f32x2 r;
    asm("v_cvt_pk_f32_fp8 %0, %1" : "=v"(r) : "s"(w));
    return r;
}

// ---------- kernel 1: fused setup (unchanged) ----------
__global__ __launch_bounds__(128)
void setup_all(const float* __restrict__ Wn, const float* __restrict__ bn,
               const float* __restrict__ We, const float* __restrict__ be,
               const float* __restrict__ Wm, const float* __restrict__ bm,
               const int* __restrict__ ei, int E,
               float* __restrict__ Wnm, float* __restrict__ bnm,
               float* __restrict__ Wc, float* __restrict__ bc,
               int* __restrict__ cnt) {
    const int b = blockIdx.x;
    const int d = threadIdx.x;
    if (b < 128) {
        float acc = 0.f;
#pragma unroll 8
        for (int j = 0; j < D; ++j)
            acc = fmaf(Wn[b * D + j], Wm[j * D + d], acc);
        Wnm[b * D + d] = acc;
    } else if (b == 128) {
        float acc = 0.f;
#pragma unroll 8
        for (int j = 0; j < D; ++j)
            acc = fmaf(bn[j], Wm[j * D + d], acc);
        bnm[d] = acc;
    } else if (b < 135) {
        const int k = b - 129;
        float acc = 0.f;
#pragma unroll 8
        for (int j = 0; j < D; ++j)
            acc = fmaf(We[k * D + j], Wm[(D + j) * D + d], acc);
        Wc[k * D + d] = acc;
    } else if (b == 135) {
        float acc = bm[d];
#pragma unroll 8
        for (int j = 0; j < D; ++j)
            acc = fmaf(be[j], Wm[(D + j) * D + d], acc);
        bc[d] = acc;
    } else {
        for (int i = (b - 136) * 128 + d; i < E; i += HIST_BLOCKS * 128)
            atomicAdd(&cnt[ei[i]], 1);
    }
}

// ---------- kernel 2: scan (+ coarse cursors) / Wb pack ----------
// CB=256 divides 1024 -> every coarse bucket contiguous within a scan block.
__global__ __launch_bounds__(1024)
void scan_pack(const int* __restrict__ cnt, int* __restrict__ start,
               int* __restrict__ cur2, int* __restrict__ cursor, int n, int nscan,
               const float* __restrict__ Wn, const float* __restrict__ Wnm,
               unsigned short* __restrict__ Wb) {
    const int tid = threadIdx.x;
    if ((int)blockIdx.x >= nscan) {
        const int idx = ((int)blockIdx.x - nscan) * 1024 + tid;
        if (idx < 4096) {
            const int lane = idx & 63;
            const int s = (idx >> 6) & 3;
            const int ct = (idx >> 8) & 7;
            const int mat = idx >> 11;
            const float* W = mat ? Wnm : Wn;
            const int col = ct * 16 + (lane & 15);
            const int k0 = (lane >> 4) * 8 + 32 * s;
            short8 v;
#pragma unroll
            for (int j = 0; j < 8; ++j)
                v[j] = (short)f2bf(W[(size_t)(k0 + j) * D + col]);
            *reinterpret_cast<short8*>(Wb + (size_t)idx * 8) = v;
        }
        return;
    }
    __shared__ int wsum[16];
    __shared__ int sbase;
    const int lane = tid & 63, wid = tid >> 6;
    const int i = blockIdx.x * 1024 + tid;
    const int v = (i < n) ? cnt[i] : 0;
    int x = v;
#pragma unroll
    for (int off = 1; off < 64; off <<= 1) {
        int t = __shfl_up(x, off);
        if (lane >= off) x += t;
    }
    if (lane == 63) wsum[wid] = x;
    __syncthreads();
    if (wid == 0) {
        int w = (lane < 16) ? wsum[lane] : 0;
#pragma unroll
        for (int off = 1; off < 16; off <<= 1) {
            int t = __shfl_up(w, off);
            if (lane >= off) w += t;
        }
        if (lane < 16) wsum[lane] = w;
    }
    __syncthreads();
    const int total = wsum[15];
    if (tid == 0) sbase = atomicAdd(cursor, total);
    __syncthreads();
    const int woff = (wid > 0) ? wsum[wid - 1] : 0;
    if (i < n) {
        const int sv = sbase + woff + x - v;
        start[i] = sv;
        if ((i & (CB - 1)) == 0) cur2[i >> 8] = sv;  // coarse bucket cursor
    }
}

// ---------- kernel 3: FUSED coarse-binning scatter + dual MFMA GEMM ----------
// tmp record 8B: w0 = col | fp8(e0,e1)<<16 ; w1 = fp8(e2,e3) | fp8(e4,e5)<<16.
// rowLocal (8b) in separate byte array tmpR. Bucket runs ~10 -> L2 merges lines.
__global__ __launch_bounds__(256)
void scat_gemm(const int* __restrict__ ei, int E, const float* __restrict__ ea,
               int* __restrict__ cur2, uint2* __restrict__ tmp,
               unsigned char* __restrict__ tmpR, int nbin,
               const float* __restrict__ x, const unsigned short* __restrict__ Wb,
               const float* __restrict__ bn, const float* __restrict__ bnm,
               unsigned short* __restrict__ xtb, unsigned char* __restrict__ hb,
               int nrows) {
    __shared__ unsigned short sP[BINE * 3];  // 12 KB: 3 fp8-pairs per edge
    __shared__ int hist[NB2];
    __shared__ int cbase[NB2];
    const int tid = threadIdx.x;
    if ((int)blockIdx.x < nbin) {
        const int base = blockIdx.x * BINE;
        const int nrec = min(BINE, E - base);
        if (tid < NB2) hist[tid] = 0;
        const float2* ea2 = reinterpret_cast<const float2*>(ea);
        for (int i = tid; i < nrec * 3; i += 256) {
            float2 p = ea2[(size_t)base * 3 + i];
            sP[i] = (unsigned short)f2fp8pair(p.x, p.y);
        }
        int rows[8], cols[8];
#pragma unroll
        for (int it = 0; it < 8; ++it) {
            const int e = base + it * 256 + tid;
            const bool val = e < E;
            rows[it] = val ? ei[e] : -1;
            cols[it] = val ? ei[E + e] : 0;
        }
        __syncthreads();
#pragma unroll
        for (int it = 0; it < 8; ++it)
            if (rows[it] >= 0) atomicAdd(&hist[rows[it] >> 8], 1);
        __syncthreads();
        if (tid < NB2) {
            const int hv = hist[tid];
            cbase[tid] = hv ? atomicAdd(&cur2[tid], hv) : 0;
            hist[tid] = 0;
        }
        __syncthreads();
#pragma unroll
        for (int it = 0; it < 8; ++it)
            if (rows[it] >= 0) {
                const int bkt = rows[it] >> 8;
                const int lp = atomicAdd(&hist[bkt], 1);
                const int pos = cbase[bkt] + lp;
                const int le = (it * 256 + tid) * 3;
                const unsigned w0 = (unsigned)cols[it] | ((unsigned)sP[le] << 16);
                const unsigned w1 = (unsigned)sP[le + 1] | ((unsigned)sP[le + 2] << 16);
                tmp[pos] = make_uint2(w0, w1);
                tmpR[pos] = (unsigned char)(rows[it] & (CB - 1));
            }
        return;
    }
    // ----- dual MFMA GEMM: 4 waves/block, one 16-row tile per wave -----
    const int ntile = (nrows + 15) / 16;
    const int lane = tid & 63;
    const int wid = tid >> 6;
    const int t = ((int)blockIdx.x - nbin) * 4 + wid;
    if (t >= ntile) return;
    const int row16 = lane & 15;
    const int kgrp = lane >> 4;

    float biasA[8], biasB[8];
#pragma unroll
    for (int ct = 0; ct < 8; ++ct) {
        biasA[ct] = bn[ct * 16 + row16];
        biasB[ct] = bnm[ct * 16 + row16];
    }
    const int ra = t * 16 + row16;
    const bool rv = ra < nrows;
    short8 a[4];
#pragma unroll
    for (int s = 0; s < 4; ++s) {
        const float* xp = x + (size_t)ra * D + kgrp * 8 + 32 * s;
        float4 u0 = rv ? *reinterpret_cast<const float4*>(xp)
                       : make_float4(0.f, 0.f, 0.f, 0.f);
        float4 u1 = rv ? *reinterpret_cast<const float4*>(xp + 4)
                       : make_float4(0.f, 0.f, 0.f, 0.f);
        a[s][0] = (short)f2bf(u0.x); a[s][1] = (short)f2bf(u0.y);
        a[s][2] = (short)f2bf(u0.z); a[s][3] = (short)f2bf(u0.w);
        a[s][4] = (short)f2bf(u1.x); a[s][5] = (short)f2bf(u1.y);
        a[s][6] = (short)f2bf(u1.z); a[s][7] = (short)f2bf(u1.w);
    }
    const int rw0 = t * 16 + kgrp * 4;
#pragma unroll
    for (int mat = 0; mat < 2; ++mat) {
#pragma unroll
        for (int ct = 0; ct < 8; ++ct) {
            f32x4 acc = {0.f, 0.f, 0.f, 0.f};
#pragma unroll
            for (int s = 0; s < 4; ++s) {
                short8 bfr = *reinterpret_cast<const short8*>(
                    Wb + (size_t)((((mat * 8 + ct) * 4 + s) * 64 + lane)) * 8);
                acc = __builtin_amdgcn_mfma_f32_16x16x32_bf16(a[s], bfr, acc, 0, 0, 0);
            }
            const float bsc = mat ? biasB[ct] : biasA[ct];
            const int dcol = ct * 16 + row16;
#pragma unroll
            for (int j = 0; j < 4; ++j) {
                const int r = rw0 + j;
                if (r < nrows) {
                    if (mat == 0)
                        xtb[(size_t)r * D + dcol] = f2bf(acc[j] + bsc);
                    else
                        hb[(size_t)r * D + dcol] = (unsigned char)f2fp8(acc[j] + bsc);
                }
            }
        }
    }
}

// ---------- kernel 4: resort — coarse records -> exact node-CSR order ----------
// 196 blocks, one per coarse bucket (~4100 records, 2 LDS chunks).
__global__ __launch_bounds__(512)
void resort(const uint2* __restrict__ tmp, const unsigned char* __restrict__ tmpR,
            const int* __restrict__ start, const int* __restrict__ cnt,
            uint2* __restrict__ rec, int nnode) {
    __shared__ uint2 sRec[2048];          // 16 KB
    __shared__ unsigned char sRow[2048];  // 2 KB
    __shared__ int ncur[CB];
    const int tid = threadIdx.x;
    const int b = blockIdx.x;
    const int nodes0 = b * CB;
    const int nn = min(CB, nnode - nodes0);
    if (tid < CB) ncur[tid] = (tid < nn) ? start[nodes0 + tid] : 0;
    __syncthreads();
    const int s0 = start[nodes0];
    const int lastn = nodes0 + nn - 1;
    const int count = start[lastn] + cnt[lastn] - s0;
    for (int base = 0; base < count; base += 2048) {
        const int m = min(2048, count - base);
        for (int i = tid; i < m; i += 512) {
            sRec[i] = tmp[(size_t)(s0 + base) + i];
            sRow[i] = tmpR[(size_t)(s0 + base) + i];
        }
        __syncthreads();
        for (int i = tid; i < m; i += 512) {
            const int rl = sRow[i];
            const int pos = atomicAdd(&ncur[rl], 1);
            rec[pos] = sRec[i];
        }
        __syncthreads();
    }
}

// ---------- kernel 5: per-node gather-aggregate + residual + LayerNorm ----------
// R15 loop; 8B records (col + fp8 ea) + fp8 h.
__global__ __launch_bounds__(256)
void aggregate_ln(const unsigned char* __restrict__ h8,
                  const int* __restrict__ start, const int* __restrict__ cnt,
                  const uint2* __restrict__ rec,
                  const float* __restrict__ Wc, const float* __restrict__ bc,
                  const unsigned* __restrict__ xtb,
                  const float* __restrict__ gamma, const float* __restrict__ beta,
                  float* __restrict__ out, int nnode) {
    const int lane = threadIdx.x & 63;
    const int wid = threadIdx.x >> 6;

    f32x2 wc[EDGE_DIM];
#pragma unroll
    for (int k = 0; k < EDGE_DIM; ++k)
        wc[k] = reinterpret_cast<const f32x2*>(Wc)[k * 64 + lane];
    const f32x2 bc2 = reinterpret_cast<const f32x2*>(bc)[lane];
    const f32x2 g = reinterpret_cast<const f32x2*>(gamma)[lane];
    const f32x2 bb = reinterpret_cast<const f32x2*>(beta)[lane];

    for (int n = blockIdx.x * 4 + wid; n < nnode; n += gridDim.x * 4) {
        const int s = start[n];
        const int c = cnt[n];
        const unsigned xu = xtb[(unsigned)(n * 64 + lane)];
        f32x2 axy = {0.f, 0.f};
        for (int ibase = 0; ibase < c; ibase += 64) {
            const int m = min(64, c - ibase);
            uint2 rc = make_uint2(0, 0);
            if (lane < m) rc = rec[(size_t)(s + ibase) + lane];
            auto LDH = [&](int j) -> unsigned {
                const int jc = min(j, m - 1);
                const unsigned colj =
                    (unsigned)__builtin_amdgcn_readlane((int)rc.x, jc) & 0xffffu;
                const unsigned short* hrow =
                    reinterpret_cast<const unsigned short*>(h8 + ((size_t)colj << 7));
                return hrow[lane];  // 2 fp8 = dims (2l, 2l+1)
            };
            auto COMP = [&](int j, unsigned hv) {
                const unsigned w0 = (unsigned)__builtin_amdgcn_readlane((int)rc.x, j);
                const unsigned w1 = (unsigned)__builtin_amdgcn_readlane((int)rc.y, j);
                const f32x2 e01 = cvt2_fp8s(w0 >> 16);
                const f32x2 e23 = cvt2_fp8s(w1 & 0xffffu);
                const f32x2 e45 = cvt2_fp8s(w1 >> 16);
                const f32x2 hx = cvt2_fp8v(hv);
                f32x2 mA, mB;
                asm("v_pk_add_f32 %0, %1, %2" : "=v"(mA) : "v"(bc2), "v"(hx));
                asm("v_pk_mul_f32 %0, %1, %2 op_sel:[1,0] op_sel_hi:[1,1]"
                    : "=v"(mB) : "v"(e01), "v"(wc[1]));
                asm("v_pk_fma_f32 %0, %1, %2, %0 op_sel:[0,0,0] op_sel_hi:[0,1,1]"
                    : "+v"(mA) : "v"(e01), "v"(wc[0]));
                asm("v_pk_fma_f32 %0, %1, %2, %0 op_sel:[1,0,0] op_sel_hi:[1,1,1]"
                    : "+v"(mB) : "v"(e23), "v"(wc[3]));
                asm("v_pk_fma_f32 %0, %1, %2, %0 op_sel:[0,0,0] op_sel_hi:[0,1,1]"
                    : "+v"(mA) : "v"(e23), "v"(wc[2]));
                asm("v_pk_fma_f32 %0, %1, %2, %0 op_sel:[1,0,0] op_sel_hi:[1,1,1]"
                    : "+v"(mB) : "v"(e45), "v"(wc[5]));
                asm("v_pk_fma_f32 %0, %1, %2, %0 op_sel:[0,0,0] op_sel_hi:[0,1,1]"
                    : "+v"(mA) : "v"(e45), "v"(wc[4]));
                asm("v_pk_add_f32 %0, %0, %1" : "+v"(mA) : "v"(mB));
                axy[0] += fmaxf(mA[0], 0.f);
                axy[1] += fmaxf(mA[1], 0.f);
            };
            unsigned h0 = LDH(0), h1 = LDH(1), h2 = LDH(2), h3 = LDH(3),
                     h4 = LDH(4), h5 = LDH(5), h6 = LDH(6), h7 = LDH(7);
            int i = 0;
            for (; i + 8 <= m; i += 8) {
                COMP(i + 0, h0); h0 = LDH(i + 8);
                COMP(i + 1, h1); h1 = LDH(i + 9);
                COMP(i + 2, h2); h2 = LDH(i + 10);
                COMP(i + 3, h3); h3 = LDH(i + 11);
                COMP(i + 4, h4); h4 = LDH(i + 12);
                COMP(i + 5, h5); h5 = LDH(i + 13);
                COMP(i + 6, h6); h6 = LDH(i + 14);
                COMP(i + 7, h7); h7 = LDH(i + 15);
            }
            if (i + 0 < m) COMP(i + 0, h0);
            if (i + 1 < m) COMP(i + 1, h1);
            if (i + 2 < m) COMP(i + 2, h2);
            if (i + 3 < m) COMP(i + 3, h3);
            if (i + 4 < m) COMP(i + 4, h4);
            if (i + 5 < m) COMP(i + 5, h5);
            if (i + 6 < m) COMP(i + 6, h6);
        }
        const float inv = 1.0f / fmaxf((float)c, 1.0f);
        float o0 = fmaf(axy[0], inv, bf_lo(xu));
        float o1 = fmaf(axy[1], inv, bf_hi(xu));
        float s1 = o0 + o1, s2 = o0 * o0 + o1 * o1;
#pragma unroll
        for (int off = 32; off; off >>= 1) {
            s1 += __shfl_xor(s1, off);
            s2 += __shfl_xor(s2, off);
        }
        const float mean = s1 * (1.0f / D);
        const float var = s2 * (1.0f / D) - mean * mean;
        const float rstd = rsqrtf(var + LN_EPS);
        float2 r;
        r.x = (o0 - mean) * rstd * g[0] + bb[0];
        r.y = (o1 - mean) * rstd * g[1] + bb[1];
        reinterpret_cast<float2*>(out)[(size_t)n * 64 + lane] = r;
    }
}

extern "C" void kernel_launch(void* const* d_in, const int* in_sizes, int n_in,
                              void* d_out, int out_size, void* d_ws, size_t ws_size,
                              hipStream_t stream) {
    const float* x     = (const float*)d_in[0];
    const float* eattr = (const float*)d_in[1];
    const float* Wn    = (const float*)d_in[2];
    const float* bn    = (const float*)d_in[3];
    const float* We    = (const float*)d_in[4];
    const float* be    = (const float*)d_in[5];
    const float* Wm    = (const float*)d_in[6];
    const float* bm    = (const float*)d_in[7];
    const float* gamma = (const float*)d_in[8];
    const float* beta  = (const float*)d_in[9];
    const int*   ei    = (const int*)d_in[10];

    const int N = in_sizes[0] / D;
    const int E = in_sizes[10] / 2;

    char* ws = (char*)d_ws;
    unsigned short* xtb = (unsigned short*)ws; ws += (size_t)N * D * 2;
    unsigned char*  hb  = (unsigned char*)ws;  ws += (size_t)N * D;
    int* ints = (int*)ws;                      ws += (size_t)(N + 4) * 4;  // cnt, cursor
    int* cnt = ints;
    int* cursor = ints + N;
    int* cur2   = (int*)ws;                    ws += (size_t)(NB2 + 1) * 4;
    int* startv = (int*)ws;                    ws += (size_t)N * 4;
    uint2* rec  = (uint2*)ws;                  ws += (size_t)E * 8;
    float* Wnm  = (float*)ws;                  ws += (size_t)D * D * 4;
    float* bnm  = (float*)ws;                  ws += (size_t)D * 4;
    float* Wc   = (float*)ws;                  ws += (size_t)EDGE_DIM * D * 4;
    float* bcv  = (float*)ws;                  ws += (size_t)D * 4;
    unsigned short* Wb = (unsigned short*)ws;  ws += (size_t)4096 * 8 * 2;

    // scratch in d_out (25.6MB): tmp uint2 (6.4MB) + tmpR bytes (0.8MB);
    // aggregate_ln overwrites d_out last.
    uint2* tmp = (uint2*)d_out;
    unsigned char* tmpR = (unsigned char*)d_out + (size_t)E * 8;

    const int nscan = (N + 1023) / 1024;
    const int nbin = (E + BINE - 1) / BINE;
    const int ntile = (N + 15) / 16;

    hipMemsetAsync(ints, 0, (size_t)(N + 4) * 4, stream);

    setup_all<<<136 + HIST_BLOCKS, 128, 0, stream>>>(Wn, bn, We, be, Wm, bm, ei, E,
                                                     Wnm, bnm, Wc, bcv, cnt);
    scan_pack<<<nscan + 4, 1024, 0, stream>>>(cnt, startv, cur2, cursor, N, nscan,
                                              Wn, Wnm, Wb);
    scat_gemm<<<nbin + (ntile + 3) / 4, 256, 0, stream>>>(ei, E, eattr, cur2, tmp, tmpR,
                                                          nbin, x, Wb, bn, bnm, xtb, hb, N);
    resort<<<NB2, 512, 0, stream>>>(tmp, tmpR, startv, cnt, rec, N);
    aggregate_ln<<<(N + 3) / 4, 256, 0, stream>>>(hb, startv, cnt, rec,
                                                  Wc, bcv, (const unsigned*)xtb,
                                                  gamma, beta, (float*)d_out, N);
}